// Round 13
// baseline (352.624 us; speedup 1.0000x reference)
//
#include <hip/hip_runtime.h>

// SigWassersteinMetric: depth-4 path signature, C=10, T=256.
//   original: (4096, 256, 10) f32; generated: (1024, 256, 10) f32; sample_idx: (1024,)
//
// ROUND-13: R9 structure (1024 blocks x 256 threads, one gen/orig pair per
// block, 2 passes; thread t<250 owns 4 transposed rows = 2 ij x 2 k), but the
// LANE-VARYING LDS reads (via, vk0, vk1, vjx, vjy) are replaced by cndmask
// select-trees over the 10 wave-held uniform v registers. DS insts/step drop
// 7 -> 3 (2x b128 + 1x b64, all broadcast); +25 v_cndmask/step whose v_cmp
// masks are loop-invariant (hoisted).
//
// WHY: cross-round model (R6/R8/R9/R11) shows the LDS issue pipe is the wall:
// 55 LDS-cyc/wave-step x 2.09M wave-steps / 256 CU = 187us (measured 233);
// R8 predicts 280 (measured 283). R12's global-mirror attempt regressed
// (compiler can't s_load a kernel-written buffer -> VMEM + vmcnt stalls).
// New balance: LDS ~105us, VALU ~150us -> VALU-bound.
//
// Horner-factored Chen step (verified rounds 2/4-12):
//   A2 = S2 + (S1 + v/4) (x) v/3 ;  B2 = S2 + (S1 + v/3) (x) v/2
//   A3 = S3 + A2 (x) v/2 ;  S4' = S4 + A3 (x) v ;  S3' = S3 + B2 (x) v
//   S2' = S2 + (S1 + v/2) (x) v ;  S1 closed-form in epilogue.
#define T_LEN 256
#define C_DIM 10
#define NSTEP 255
#define BSZ   1024
#define NPAIR 1024
#define D1 10
#define D2 100
#define D3 1000
#define DTOT 11110
#define PATH_ELEMS (T_LEN * C_DIM)   // 2560
#define DX_ELEMS (NSTEP * C_DIM)     // 2550
#define DXROW 12                     // padded dx row stride (48 B, 16B-aligned)

__global__ __launch_bounds__(256)
__attribute__((amdgpu_waves_per_eu(4, 4)))
void sig_accum_kernel(
    const float* __restrict__ original,
    const float* __restrict__ generated,
    const int* __restrict__ sample_idx,
    float* __restrict__ ws, int nrep, int store_mode)
{
    const int tid = threadIdx.x;
    const int b   = blockIdx.x;

    __shared__ float s_dx[NSTEP * DXROW];  // 12240 B

    const float* path_gen  = generated + (size_t)b * PATH_ELEMS;
    const float* path_orig = original + (size_t)sample_idx[b] * PATH_ELEMS;

    const int mbase = 2 * tid;               // valid tid<250
    const int k0  = mbase / 100;             // 0..4
    const int ij0 = mbase - k0 * 100;        // even
    const int ia  = ij0 / 10;                // 0..9
    const int j0  = ij0 - ia * 10;           // even

    // Loop-invariant per-lane select bits (v_cmp hoisted out of the loop).
    const bool kb0 = (k0 & 1);
    const bool kb1 = ((k0 >> 1) & 1);
    const bool kb2 = (k0 == 4);
    const int  r5  = (ia >= 5) ? (ia - 5) : ia;
    const bool ib0 = (r5 & 1);
    const bool ib1 = ((r5 >> 1) & 1);
    const bool ib2 = (r5 == 4);
    const bool ih  = (ia >= 5);
    const int  e   = j0 >> 1;                // 0..4
    const bool eb0 = (e & 1);
    const bool eb1 = ((e >> 1) & 1);
    const bool eb2 = (e == 4);

    float s1a = 0.0f;
    float s2[2]  = {0.0f, 0.0f};
    float s2o[2] = {0.0f, 0.0f};
    float s3[4]  = {0.0f, 0.0f, 0.0f, 0.0f};   // [q]=(ij0+q,k0), [2+q]=(ij0+q,k0+5)
    float s3o[4] = {0.0f, 0.0f, 0.0f, 0.0f};
    float acc[4][10];
    #pragma unroll
    for (int r = 0; r < 4; ++r)
        #pragma unroll
        for (int l = 0; l < 10; ++l) acc[r][l] = 0.0f;

    #pragma unroll 1
    for (int pass = 0; pass < 2; ++pass) {
        const float* path = (pass == 0) ? path_gen : path_orig;

        for (int idx = tid; idx < DX_ELEMS; idx += 256) {
            int t = idx / C_DIM, c = idx - t * C_DIM;
            s_dx[t * DXROW + c] = path[idx + C_DIM] - path[idx];
        }
        __syncthreads();

        if (tid < 250) {
            const float* vrow = s_dx;
            #pragma unroll 1
            for (int t = 0; t < NSTEP; ++t, vrow += DXROW) {
                // 3 broadcast LDS reads; all other operands come from selects.
                const float4 va = *(const float4*)(vrow);
                const float4 vb = *(const float4*)(vrow + 4);
                const float2 vc = *(const float2*)(vrow + 8);
                const float v0 = va.x, v1 = va.y, v2 = va.z, v3 = va.w;
                const float v4 = vb.x, v5 = vb.y, v6 = vb.z, v7 = vb.w;
                const float v8 = vc.x, v9 = vc.y;

                // vk0 = v[k0] (k0 in 0..4); vk1 = v[k0+5]
                const float a01 = kb0 ? v1 : v0, a23 = kb0 ? v3 : v2;
                const float a03 = kb1 ? a23 : a01;
                const float vk0 = kb2 ? v4 : a03;
                const float b56 = kb0 ? v6 : v5, b78 = kb0 ? v8 : v7;
                const float b58 = kb1 ? b78 : b56;
                const float vk1 = kb2 ? v9 : b58;
                // via = v[ia] (ia in 0..9)
                const float c01 = ib0 ? v1 : v0, c23 = ib0 ? v3 : v2;
                const float c03 = ib1 ? c23 : c01;
                const float lo  = ib2 ? v4 : c03;
                const float d56 = ib0 ? v6 : v5, d78 = ib0 ? v8 : v7;
                const float d58 = ib1 ? d78 : d56;
                const float hi  = ib2 ? v9 : d58;
                const float via = ih ? hi : lo;
                // vjx = v[j0] (even), vjy = v[j0+1] (odd)
                const float e02 = eb0 ? v2 : v0, e46 = eb0 ? v6 : v4;
                const float e06 = eb1 ? e46 : e02;
                const float vjx = eb2 ? v8 : e06;
                const float f13 = eb0 ? v3 : v1, f57 = eb0 ? v7 : v5;
                const float f17 = eb1 ? f57 : f13;
                const float vjy = eb2 ? v9 : f17;

                const float vk0h = vk0 * 0.5f;
                const float vk1h = vk1 * 0.5f;
                const float t1 = s1a + via * 0.25f;
                const float t2 = s1a + via * (1.0f / 3.0f);
                const float t3 = s1a + via * 0.5f;
                const float vv[10] = {v0, v1, v2, v3, v4, v5, v6, v7, v8, v9};

                #pragma unroll
                for (int q = 0; q < 2; ++q) {
                    const float vjq = (q == 0) ? vjx : vjy;
                    const float a2 = fmaf(t1, vjq * (1.0f / 3.0f), s2[q]);
                    const float b2 = fmaf(t2, vjq * 0.5f, s2[q]);
                    s2[q] = fmaf(t3, vjq, s2[q]);

                    const float a3x = fmaf(a2, vk0h, s3[q]);
                    s3[q] = fmaf(b2, vk0, s3[q]);
                    #pragma unroll
                    for (int l = 0; l < 10; ++l)
                        acc[q][l] = fmaf(a3x, vv[l], acc[q][l]);

                    const float a3y = fmaf(a2, vk1h, s3[2 + q]);
                    s3[2 + q] = fmaf(b2, vk1, s3[2 + q]);
                    #pragma unroll
                    for (int l = 0; l < 10; ++l)
                        acc[2 + q][l] = fmaf(a3y, vv[l], acc[2 + q][l]);
                }
                s1a += via;
            }
        }

        if (pass == 0) {
            // Save negated pass-0 (generated) results; reset; negate acc so the
            // running total ends as sig_orig - sig_gen.
            #pragma unroll
            for (int q = 0; q < 2; ++q) { s2o[q] = -s2[q]; s2[q] = 0.0f; }
            #pragma unroll
            for (int r = 0; r < 4; ++r) {
                s3o[r] = -s3[r];  s3[r] = 0.0f;
                #pragma unroll
                for (int l = 0; l < 10; ++l) acc[r][l] = -acc[r][l];
            }
            s1a = 0.0f;
            __syncthreads();   // all readers of s_dx done before restaging
        }
    }

    // ---- Epilogue: signed difference row (orig - gen) ----
    if (store_mode) {
        float* row = ws + (size_t)b * DTOT;
        if (tid < D1)
            row[tid] = (path_orig[(T_LEN - 1) * C_DIM + tid] - path_orig[tid])
                     - (path_gen[(T_LEN - 1) * C_DIM + tid] - path_gen[tid]);
        if (tid < 50) {       // k0 == 0 threads own ij0 = 2*tid
            row[D1 + ij0]     = s2o[0] + s2[0];
            row[D1 + ij0 + 1] = s2o[1] + s2[1];
        }
        if (tid < 250) {
            #pragma unroll
            for (int ch = 0; ch < 2; ++ch) {          // ch=0 -> k0, ch=1 -> k0+5
                const int kk = k0 + 5 * ch;
                #pragma unroll
                for (int q = 0; q < 2; ++q) {
                    const int idx3 = (ij0 + q) * 10 + kk;
                    row[D1 + D2 + idx3] = s3o[ch * 2 + q] + s3[ch * 2 + q];
                    float* p4 = row + D1 + D2 + D3 + (size_t)idx3 * 10;
                    #pragma unroll
                    for (int l = 0; l < 10; l += 2)
                        *(float2*)&p4[l] = make_float2(acc[ch * 2 + q][l],
                                                       acc[ch * 2 + q][l + 1]);
                }
            }
        }
    } else {
        float* base = ws + (size_t)(b % nrep) * DTOT;
        if (tid < D1)
            atomicAdd(&base[tid],
                      (path_orig[(T_LEN - 1) * C_DIM + tid] - path_orig[tid])
                    - (path_gen[(T_LEN - 1) * C_DIM + tid] - path_gen[tid]));
        if (tid < 50) {
            atomicAdd(&base[D1 + ij0],     s2o[0] + s2[0]);
            atomicAdd(&base[D1 + ij0 + 1], s2o[1] + s2[1]);
        }
        if (tid < 250) {
            #pragma unroll
            for (int ch = 0; ch < 2; ++ch) {
                const int kk = k0 + 5 * ch;
                #pragma unroll
                for (int q = 0; q < 2; ++q) {
                    const int idx3 = (ij0 + q) * 10 + kk;
                    atomicAdd(&base[D1 + D2 + idx3], s3o[ch * 2 + q] + s3[ch * 2 + q]);
                    #pragma unroll
                    for (int l = 0; l < 10; ++l)
                        atomicAdd(&base[D1 + D2 + D3 + idx3 * 10 + l],
                                  acc[ch * 2 + q][l]);
                }
            }
        }
    }
}

// Stage 1: block sums 32 rows for a float2 d-tile (coalesced), atomically
// accumulates into accvec[DTOT]. Grid: (ceil(5555/256), 32).
__global__ __launch_bounds__(256) void sig_sum_kernel(
    const float* __restrict__ ws, float* __restrict__ accvec)
{
    const int d2 = blockIdx.x * 256 + threadIdx.x;   // DTOT/2 = 5555
    if (d2 >= DTOT / 2) return;
    const float* p = ws + (size_t)(blockIdx.y * 32) * DTOT + 2 * d2;
    float sx = 0.0f, sy = 0.0f;
    #pragma unroll
    for (int r = 0; r < 32; ++r) {
        const float2 v = *(const float2*)(p + (size_t)r * DTOT);
        sx += v.x; sy += v.y;
    }
    atomicAdd(&accvec[2 * d2], sx);
    atomicAdd(&accvec[2 * d2 + 1], sy);
}

// Stage 2: sum of squares -> sumsq; last block writes the norm.
__global__ __launch_bounds__(256) void sig_sumsq_kernel(
    const float* __restrict__ accvec, float* __restrict__ sumsq,
    unsigned int* __restrict__ counter, float* __restrict__ out, int nblocks)
{
    const int d = blockIdx.x * 256 + threadIdx.x;
    float s = 0.0f;
    if (d < DTOT) { float v = accvec[d]; s = v * v; }
    for (int off = 32; off > 0; off >>= 1) s += __shfl_down(s, off, 64);
    __shared__ float red[4];
    __shared__ unsigned int lastflag;
    if ((threadIdx.x & 63) == 0) red[threadIdx.x >> 6] = s;
    __syncthreads();
    if (threadIdx.x == 0) {
        atomicAdd(sumsq, red[0] + red[1] + red[2] + red[3]);
        __threadfence();
        lastflag = (atomicAdd(counter, 1u) == (unsigned int)(nblocks - 1));
    }
    __syncthreads();
    if (threadIdx.x == 0 && lastflag) {
        __threadfence();
        out[0] = sqrtf(*(volatile float*)sumsq) * (1.0f / (float)BSZ);
    }
}

// Fallback reduce for small-ws atomic-replica modes.
__global__ __launch_bounds__(256) void sig_reduce_kernel(
    const float* __restrict__ ws, int nrows, float* __restrict__ sumsq,
    unsigned int* __restrict__ counter, float* __restrict__ out, int nblocks)
{
    const int d = blockIdx.x * 256 + threadIdx.x;
    float s = 0.0f;
    if (d < DTOT) {
        for (int r = 0; r < nrows; ++r) s += ws[(size_t)r * DTOT + d];
        s = s * s;
    }
    for (int off = 32; off > 0; off >>= 1) s += __shfl_down(s, off, 64);
    __shared__ float red[4];
    __shared__ unsigned int lastflag;
    if ((threadIdx.x & 63) == 0) red[threadIdx.x >> 6] = s;
    __syncthreads();
    if (threadIdx.x == 0) {
        atomicAdd(sumsq, red[0] + red[1] + red[2] + red[3]);
        __threadfence();
        lastflag = (atomicAdd(counter, 1u) == (unsigned int)(nblocks - 1));
    }
    __syncthreads();
    if (threadIdx.x == 0 && lastflag) {
        __threadfence();
        out[0] = sqrtf(*(volatile float*)sumsq) * (1.0f / (float)BSZ);
    }
}

extern "C" void kernel_launch(void* const* d_in, const int* in_sizes, int n_in,
                              void* d_out, int out_size, void* d_ws, size_t ws_size,
                              hipStream_t stream) {
    const float* original   = (const float*)d_in[0];
    const float* generated  = (const float*)d_in[1];
    const int*   sample_idx = (const int*)d_in[2];
    float* out = (float*)d_out;
    float* ws  = (float*)d_ws;

    // Layout: rows [0, NPAIR*DTOT), accvec [+DTOT), sumsq [+1), counter [+1)
    const size_t need_store = ((size_t)(NPAIR + 1) * DTOT + 2) * sizeof(float);

    if (ws_size >= need_store) {
        float* accvec = ws + (size_t)NPAIR * DTOT;
        float* sumsq  = accvec + DTOT;
        unsigned int* counter = (unsigned int*)(sumsq + 1);
        hipMemsetAsync(accvec, 0, (DTOT + 2) * sizeof(float), stream);
        sig_accum_kernel<<<NPAIR, 256, 0, stream>>>(original, generated, sample_idx,
                                                    ws, 1, 1);
        dim3 g1((DTOT / 2 + 255) / 256, 32);
        sig_sum_kernel<<<g1, 256, 0, stream>>>(ws, accvec);
        const int nb2 = (DTOT + 255) / 256;
        sig_sumsq_kernel<<<nb2, 256, 0, stream>>>(accvec, sumsq, counter, out, nb2);
    } else {
        int nrep = 1;
        if (ws_size >= ((size_t)64 * DTOT + 2) * sizeof(float)) nrep = 64;
        else if (ws_size >= ((size_t)8 * DTOT + 2) * sizeof(float)) nrep = 8;
        float* sumsq = ws + (size_t)nrep * DTOT;
        unsigned int* counter = (unsigned int*)(sumsq + 1);
        hipMemsetAsync(ws, 0, ((size_t)nrep * DTOT + 2) * sizeof(float), stream);
        sig_accum_kernel<<<NPAIR, 256, 0, stream>>>(original, generated, sample_idx,
                                                    ws, nrep, 0);
        const int nb2 = (DTOT + 255) / 256;
        sig_reduce_kernel<<<nb2, 256, 0, stream>>>(ws, nrep, sumsq, counter, out, nb2);
    }
}

// Round 14
// 285.594 us; speedup vs baseline: 1.2347x; 1.2347x over previous
//
#include <hip/hip_runtime.h>

// SigWassersteinMetric: depth-4 path signature, C=10, T=256.
//   original: (4096, 256, 10) f32; generated: (1024, 256, 10) f32; sample_idx: (1024,)
//
// ROUND-14: exact R9 math/layout (best passing round: accum 233us, total 292),
// with the per-step LDS stall removed:
//   - #pragma unroll 2 on the t-loop: scheduler hoists step t+1's three
//     broadcast ds_reads above step t's 64-FMA body (prefetch depth 1).
//   - dropped amdgpu_waves_per_eu(4,4): grid (4096 waves / 1024 SIMDs) limits
//     residency, not the attribute; the pin only constrained the allocator.
//
// MODEL (R6/R9/R13 cross-check): kernel is VALU-issue bound at ~65% of
// nominal FP32 issue (m07 ubench: 103/157 TF). R6 and R9 have equal total
// VALU wave-inst (~134M) and equal time (233us); R13 raised inst 1.47x ->
// time 1.31x. 134M inst at measured rate = 166us; the 67us residue matches
// the 21% VALUBusy gap = per-iteration lgkmcnt stalls (unroll 1, 4 waves/SIMD).
//
// Horner-factored Chen step (verified rounds 2/4-13):
//   A2 = S2 + (S1 + v/4) (x) v/3 ;  B2 = S2 + (S1 + v/3) (x) v/2
//   A3 = S3 + A2 (x) v/2 ;  S4' = S4 + A3 (x) v ;  S3' = S3 + B2 (x) v
//   S2' = S2 + (S1 + v/2) (x) v ;  S1 closed-form in epilogue.
#define T_LEN 256
#define C_DIM 10
#define NSTEP 255
#define BSZ   1024
#define NPAIR 1024
#define D1 10
#define D2 100
#define D3 1000
#define DTOT 11110
#define PATH_ELEMS (T_LEN * C_DIM)   // 2560
#define DX_ELEMS (NSTEP * C_DIM)     // 2550
#define DXROW 12                     // padded dx row stride (48 B, 16B-aligned)

__global__ __launch_bounds__(256)
void sig_accum_kernel(
    const float* __restrict__ original,
    const float* __restrict__ generated,
    const int* __restrict__ sample_idx,
    float* __restrict__ ws, int nrep, int store_mode)
{
    const int tid = threadIdx.x;
    const int b   = blockIdx.x;

    __shared__ float s_dx[NSTEP * DXROW];  // 12240 B

    const float* path_gen  = generated + (size_t)b * PATH_ELEMS;
    const float* path_orig = original + (size_t)sample_idx[b] * PATH_ELEMS;

    const int mbase = 2 * tid;               // valid tid<250
    const int k0  = mbase / 100;             // 0..4
    const int ij0 = mbase - k0 * 100;        // even
    const int ia  = ij0 / 10;
    const int j0  = ij0 - ia * 10;           // even -> (j0, j0+1) same decade

    float s1a = 0.0f;
    float s2[2]  = {0.0f, 0.0f};
    float s2o[2] = {0.0f, 0.0f};
    float s3[4]  = {0.0f, 0.0f, 0.0f, 0.0f};   // [q]=(ij0+q,k0), [2+q]=(ij0+q,k0+5)
    float s3o[4] = {0.0f, 0.0f, 0.0f, 0.0f};
    float acc[4][10];
    #pragma unroll
    for (int r = 0; r < 4; ++r)
        #pragma unroll
        for (int l = 0; l < 10; ++l) acc[r][l] = 0.0f;

    #pragma unroll 1
    for (int pass = 0; pass < 2; ++pass) {
        const float* path = (pass == 0) ? path_gen : path_orig;

        for (int idx = tid; idx < DX_ELEMS; idx += 256) {
            int t = idx / C_DIM, c = idx - t * C_DIM;
            s_dx[t * DXROW + c] = path[idx + C_DIM] - path[idx];
        }
        __syncthreads();

        if (tid < 250) {
            const float* vrow = s_dx;
            #pragma unroll 2
            for (int t = 0; t < NSTEP; ++t, vrow += DXROW) {
                const float4 va = *(const float4*)(vrow);       // v0..v3 (uniform)
                const float4 vb = *(const float4*)(vrow + 4);   // v4..v7 (uniform)
                const float2 vc = *(const float2*)(vrow + 8);   // v8,v9  (uniform)
                const float2 vjp = *(const float2*)(vrow + j0); // vj for q0,q1
                const float via = vrow[ia];
                const float vk0 = vrow[k0];
                const float vk1 = vrow[k0 + 5];

                const float vv[10] = {va.x, va.y, va.z, va.w,
                                      vb.x, vb.y, vb.z, vb.w, vc.x, vc.y};
                const float vk0h = vk0 * 0.5f;
                const float vk1h = vk1 * 0.5f;
                const float t1 = s1a + via * 0.25f;
                const float t2 = s1a + via * (1.0f / 3.0f);
                const float t3 = s1a + via * 0.5f;

                #pragma unroll
                for (int q = 0; q < 2; ++q) {
                    const float vjq = (q == 0) ? vjp.x : vjp.y;
                    const float a2 = fmaf(t1, vjq * (1.0f / 3.0f), s2[q]);
                    const float b2 = fmaf(t2, vjq * 0.5f, s2[q]);
                    s2[q] = fmaf(t3, vjq, s2[q]);

                    const float a3x = fmaf(a2, vk0h, s3[q]);
                    s3[q] = fmaf(b2, vk0, s3[q]);
                    #pragma unroll
                    for (int l = 0; l < 10; ++l)
                        acc[q][l] = fmaf(a3x, vv[l], acc[q][l]);

                    const float a3y = fmaf(a2, vk1h, s3[2 + q]);
                    s3[2 + q] = fmaf(b2, vk1, s3[2 + q]);
                    #pragma unroll
                    for (int l = 0; l < 10; ++l)
                        acc[2 + q][l] = fmaf(a3y, vv[l], acc[2 + q][l]);
                }
                s1a += via;
            }
        }

        if (pass == 0) {
            // Save negated pass-0 (generated) results; reset; negate acc so the
            // running total ends as sig_orig - sig_gen.
            #pragma unroll
            for (int q = 0; q < 2; ++q) { s2o[q] = -s2[q]; s2[q] = 0.0f; }
            #pragma unroll
            for (int r = 0; r < 4; ++r) {
                s3o[r] = -s3[r];  s3[r] = 0.0f;
                #pragma unroll
                for (int l = 0; l < 10; ++l) acc[r][l] = -acc[r][l];
            }
            s1a = 0.0f;
            __syncthreads();   // all readers of s_dx done before restaging
        }
    }

    // ---- Epilogue: signed difference row (orig - gen) ----
    if (store_mode) {
        float* row = ws + (size_t)b * DTOT;
        if (tid < D1)
            row[tid] = (path_orig[(T_LEN - 1) * C_DIM + tid] - path_orig[tid])
                     - (path_gen[(T_LEN - 1) * C_DIM + tid] - path_gen[tid]);
        if (tid < 50) {       // k0 == 0 threads own ij0 = 2*tid
            row[D1 + ij0]     = s2o[0] + s2[0];
            row[D1 + ij0 + 1] = s2o[1] + s2[1];
        }
        if (tid < 250) {
            #pragma unroll
            for (int ch = 0; ch < 2; ++ch) {          // ch=0 -> k0, ch=1 -> k0+5
                const int kk = k0 + 5 * ch;
                #pragma unroll
                for (int q = 0; q < 2; ++q) {
                    const int idx3 = (ij0 + q) * 10 + kk;
                    row[D1 + D2 + idx3] = s3o[ch * 2 + q] + s3[ch * 2 + q];
                    float* p4 = row + D1 + D2 + D3 + (size_t)idx3 * 10;
                    #pragma unroll
                    for (int l = 0; l < 10; l += 2)
                        *(float2*)&p4[l] = make_float2(acc[ch * 2 + q][l],
                                                       acc[ch * 2 + q][l + 1]);
                }
            }
        }
    } else {
        float* base = ws + (size_t)(b % nrep) * DTOT;
        if (tid < D1)
            atomicAdd(&base[tid],
                      (path_orig[(T_LEN - 1) * C_DIM + tid] - path_orig[tid])
                    - (path_gen[(T_LEN - 1) * C_DIM + tid] - path_gen[tid]));
        if (tid < 50) {
            atomicAdd(&base[D1 + ij0],     s2o[0] + s2[0]);
            atomicAdd(&base[D1 + ij0 + 1], s2o[1] + s2[1]);
        }
        if (tid < 250) {
            #pragma unroll
            for (int ch = 0; ch < 2; ++ch) {
                const int kk = k0 + 5 * ch;
                #pragma unroll
                for (int q = 0; q < 2; ++q) {
                    const int idx3 = (ij0 + q) * 10 + kk;
                    atomicAdd(&base[D1 + D2 + idx3], s3o[ch * 2 + q] + s3[ch * 2 + q]);
                    #pragma unroll
                    for (int l = 0; l < 10; ++l)
                        atomicAdd(&base[D1 + D2 + D3 + idx3 * 10 + l],
                                  acc[ch * 2 + q][l]);
                }
            }
        }
    }
}

// Stage 1: block sums 32 rows for a float2 d-tile (coalesced), atomically
// accumulates into accvec[DTOT]. Grid: (ceil(5555/256), 32).
__global__ __launch_bounds__(256) void sig_sum_kernel(
    const float* __restrict__ ws, float* __restrict__ accvec)
{
    const int d2 = blockIdx.x * 256 + threadIdx.x;   // DTOT/2 = 5555
    if (d2 >= DTOT / 2) return;
    const float* p = ws + (size_t)(blockIdx.y * 32) * DTOT + 2 * d2;
    float sx = 0.0f, sy = 0.0f;
    #pragma unroll
    for (int r = 0; r < 32; ++r) {
        const float2 v = *(const float2*)(p + (size_t)r * DTOT);
        sx += v.x; sy += v.y;
    }
    atomicAdd(&accvec[2 * d2], sx);
    atomicAdd(&accvec[2 * d2 + 1], sy);
}

// Stage 2: sum of squares -> sumsq; last block writes the norm.
__global__ __launch_bounds__(256) void sig_sumsq_kernel(
    const float* __restrict__ accvec, float* __restrict__ sumsq,
    unsigned int* __restrict__ counter, float* __restrict__ out, int nblocks)
{
    const int d = blockIdx.x * 256 + threadIdx.x;
    float s = 0.0f;
    if (d < DTOT) { float v = accvec[d]; s = v * v; }
    for (int off = 32; off > 0; off >>= 1) s += __shfl_down(s, off, 64);
    __shared__ float red[4];
    __shared__ unsigned int lastflag;
    if ((threadIdx.x & 63) == 0) red[threadIdx.x >> 6] = s;
    __syncthreads();
    if (threadIdx.x == 0) {
        atomicAdd(sumsq, red[0] + red[1] + red[2] + red[3]);
        __threadfence();
        lastflag = (atomicAdd(counter, 1u) == (unsigned int)(nblocks - 1));
    }
    __syncthreads();
    if (threadIdx.x == 0 && lastflag) {
        __threadfence();
        out[0] = sqrtf(*(volatile float*)sumsq) * (1.0f / (float)BSZ);
    }
}

// Fallback reduce for small-ws atomic-replica modes.
__global__ __launch_bounds__(256) void sig_reduce_kernel(
    const float* __restrict__ ws, int nrows, float* __restrict__ sumsq,
    unsigned int* __restrict__ counter, float* __restrict__ out, int nblocks)
{
    const int d = blockIdx.x * 256 + threadIdx.x;
    float s = 0.0f;
    if (d < DTOT) {
        for (int r = 0; r < nrows; ++r) s += ws[(size_t)r * DTOT + d];
        s = s * s;
    }
    for (int off = 32; off > 0; off >>= 1) s += __shfl_down(s, off, 64);
    __shared__ float red[4];
    __shared__ unsigned int lastflag;
    if ((threadIdx.x & 63) == 0) red[threadIdx.x >> 6] = s;
    __syncthreads();
    if (threadIdx.x == 0) {
        atomicAdd(sumsq, red[0] + red[1] + red[2] + red[3]);
        __threadfence();
        lastflag = (atomicAdd(counter, 1u) == (unsigned int)(nblocks - 1));
    }
    __syncthreads();
    if (threadIdx.x == 0 && lastflag) {
        __threadfence();
        out[0] = sqrtf(*(volatile float*)sumsq) * (1.0f / (float)BSZ);
    }
}

extern "C" void kernel_launch(void* const* d_in, const int* in_sizes, int n_in,
                              void* d_out, int out_size, void* d_ws, size_t ws_size,
                              hipStream_t stream) {
    const float* original   = (const float*)d_in[0];
    const float* generated  = (const float*)d_in[1];
    const int*   sample_idx = (const int*)d_in[2];
    float* out = (float*)d_out;
    float* ws  = (float*)d_ws;

    // Layout: rows [0, NPAIR*DTOT), accvec [+DTOT), sumsq [+1), counter [+1)
    const size_t need_store = ((size_t)(NPAIR + 1) * DTOT + 2) * sizeof(float);

    if (ws_size >= need_store) {
        float* accvec = ws + (size_t)NPAIR * DTOT;
        float* sumsq  = accvec + DTOT;
        unsigned int* counter = (unsigned int*)(sumsq + 1);
        hipMemsetAsync(accvec, 0, (DTOT + 2) * sizeof(float), stream);
        sig_accum_kernel<<<NPAIR, 256, 0, stream>>>(original, generated, sample_idx,
                                                    ws, 1, 1);
        dim3 g1((DTOT / 2 + 255) / 256, 32);
        sig_sum_kernel<<<g1, 256, 0, stream>>>(ws, accvec);
        const int nb2 = (DTOT + 255) / 256;
        sig_sumsq_kernel<<<nb2, 256, 0, stream>>>(accvec, sumsq, counter, out, nb2);
    } else {
        int nrep = 1;
        if (ws_size >= ((size_t)64 * DTOT + 2) * sizeof(float)) nrep = 64;
        else if (ws_size >= ((size_t)8 * DTOT + 2) * sizeof(float)) nrep = 8;
        float* sumsq = ws + (size_t)nrep * DTOT;
        unsigned int* counter = (unsigned int*)(sumsq + 1);
        hipMemsetAsync(ws, 0, ((size_t)nrep * DTOT + 2) * sizeof(float), stream);
        sig_accum_kernel<<<NPAIR, 256, 0, stream>>>(original, generated, sample_idx,
                                                    ws, nrep, 0);
        const int nb2 = (DTOT + 255) / 256;
        sig_reduce_kernel<<<nb2, 256, 0, stream>>>(ws, nrep, sumsq, counter, out, nb2);
    }
}